// Round 13
// baseline (1143.638 us; speedup 1.0000x reference)
//
#include <hip/hip_runtime.h>

#define NN 50000
#define NE 800000
#define BG 512
#define HD 128
#define GD 32
#define MD 128
#define EPSV 1e-5f
#define NBK 256   // dst buckets
#define BSTR 196  // dst per bucket (196*256 = 50176 >= NN)
#define BCAP 4096 // edge capacity per bucket (mean 3136, sd ~56)
#define SP 136    // LDS row stride (shorts) for gemm tiles

typedef __attribute__((ext_vector_type(8))) short bf16x8;
typedef __attribute__((ext_vector_type(4))) float f32x4;

// bf16 helpers (RNE pack, cheap unpack)
static __device__ __forceinline__ unsigned short f2bf(float f) {
    unsigned int u = __float_as_uint(f);
    u += 0x7fffu + ((u >> 16) & 1u);
    return (unsigned short)(u >> 16);
}
static __device__ __forceinline__ float bfu(unsigned short v) {
    return __uint_as_float((unsigned int)v << 16);
}
static __device__ __forceinline__ float bf_lo(unsigned int v) {
    return __uint_as_float(v << 16);
}
static __device__ __forceinline__ float bf_hi(unsigned int v) {
    return __uint_as_float(v & 0xffff0000u);
}

// ---------------- Pass 1: bin edges by dst bucket ----------------
__global__ __launch_bounds__(256) void k_bin(const int* __restrict__ src,
                                             const int* __restrict__ dst,
                                             int* __restrict__ bucket_cnt,
                                             unsigned int* __restrict__ binned) {
    __shared__ int hcnt[NBK];
    __shared__ int hbase[NBK];
    int tid = threadIdx.x;
    int e0 = blockIdx.x * 2048;
    unsigned int pv[8];
    int bk[8], rk[8];
#pragma unroll
    for (int i = 0; i < 8; ++i) {
        int e = e0 + i * 256 + tid;
        if (e < NE) {
            int s = src[e];
            int d = dst[e];
            bk[i] = d / BSTR;
            pv[i] = ((unsigned int)(d - bk[i] * BSTR) << 16) | (unsigned int)s;
        } else {
            bk[i] = -1;
        }
    }
    hcnt[tid] = 0;
    __syncthreads();
#pragma unroll
    for (int i = 0; i < 8; ++i)
        if (bk[i] >= 0) rk[i] = atomicAdd(&hcnt[bk[i]], 1);
    __syncthreads();
    hbase[tid] = atomicAdd(&bucket_cnt[tid], hcnt[tid]);
    __syncthreads();
#pragma unroll
    for (int i = 0; i < 8; ++i)
        if (bk[i] >= 0)
            binned[(size_t)bk[i] * BCAP + hbase[bk[i]] + rk[i]] = pv[i];
}

// ---------------- CSR build (blocks 0..255) + W transpose (blocks 256..258) ----------------
__global__ __launch_bounds__(256) void k_csr(const unsigned int* __restrict__ binned,
                                             const int* __restrict__ bucket_cnt,
                                             int* __restrict__ offsets,
                                             float* __restrict__ dinv,
                                             int* __restrict__ csr,
                                             const float* __restrict__ W0,
                                             const float* __restrict__ W1,
                                             const float* __restrict__ W2,
                                             unsigned short* __restrict__ Wt) {
    __shared__ unsigned short sW[128 * 130];
    __shared__ int ls[256];
    __shared__ int h[BSTR];
    __shared__ int cur[BSTR];
    __shared__ int bpre_s;
    int b = blockIdx.x, t = threadIdx.x;
    if (b >= NBK) {
        const float* Wsrc = (b == NBK) ? W0 : ((b == NBK + 1) ? W1 : W2);
#pragma unroll
        for (int i = 0; i < 64; ++i) {
            int idx = i * 256 + t;
            int k = idx >> 7, n = idx & 127;
            sW[n * 130 + k] = f2bf(Wsrc[idx]);
        }
        __syncthreads();
        unsigned short* o = Wt + (size_t)(b - NBK) * 16384;
#pragma unroll
        for (int i = 0; i < 64; ++i) {
            int idx = i * 256 + t;
            int n = idx >> 7, k = idx & 127;
            o[idx] = sW[n * 130 + k];
        }
        return;
    }
    int bc = bucket_cnt[t];
    ls[t] = bc;
    __syncthreads();
    for (int off = 1; off < 256; off <<= 1) {
        int c0 = ls[t];
        int add = (t >= off) ? ls[t - off] : 0;
        __syncthreads();
        ls[t] = c0 + add;
        __syncthreads();
    }
    if (t == b) bpre_s = ls[t] - bc;
    if (t < BSTR) h[t] = 0;
    __syncthreads();
    int bpre = bpre_s;
    int nb = bucket_cnt[b];
    const unsigned int* base = binned + (size_t)b * BCAP;
    for (int e = t; e < nb; e += 256)
        atomicAdd(&h[base[e] >> 16], 1);
    __syncthreads();
    int c = (t < BSTR) ? h[t] : 0;
    ls[t] = c;
    __syncthreads();
    for (int off = 1; off < 256; off <<= 1) {
        int c0 = ls[t];
        int add = (t >= off) ? ls[t - off] : 0;
        __syncthreads();
        ls[t] = c0 + add;
        __syncthreads();
    }
    int node = b * BSTR + t;
    if (t < BSTR) {
        int excl = ls[t] - c + bpre;
        cur[t] = excl;
        if (node < NN) {
            offsets[node] = excl;
            dinv[node] = rsqrtf((float)(c + 1));  // in-degree + self loop
            if (node == NN - 1) offsets[NN] = NE;
        }
    }
    __syncthreads();
    for (int e = t; e < nb; e += 256) {
        unsigned int v = base[e];
        int pos = atomicAdd(&cur[v >> 16], 1);
        csr[pos] = (int)(v & 0xffffu);
    }
}

// ---------------- MFMA GEMM (LDS-staged): Th(bf16) = dinv[row] * (BNReLU?(In) @ W) ----------------
// LDS staging: Wt fragments shared across the block's 4 waves (removing it
// regressed R11 — reuse is across waves). BN scales from compact stats[256].
__global__ __launch_bounds__(256) void k_gemm(const float* __restrict__ Inf,
                                              const unsigned short* __restrict__ Inh,
                                              const unsigned short* __restrict__ Wt,
                                              unsigned short* __restrict__ Th,
                                              const float* __restrict__ stats,
                                              const float* __restrict__ gamma,
                                              const float* __restrict__ beta,
                                              const float* __restrict__ dinv,
                                              int useBN) {
    __shared__ unsigned short Abf[64 * SP];
    __shared__ unsigned short WtL[128 * SP];
    __shared__ float ssS[256];
    int tid = threadIdx.x;
    int rowBase = blockIdx.x * 64;
    if (useBN) {
        ssS[tid] = stats[tid];
        __syncthreads();
        if (tid < 128) {
            float mu = ssS[tid] * (1.f / NN);
            float var = ssS[128 + tid] * (1.f / NN) - mu * mu;
            float sc = gamma[tid] * rsqrtf(var + EPSV);
            float sh = beta[tid] - mu * sc;
            ssS[tid] = sc;
            ssS[128 + tid] = sh;
        }
        __syncthreads();
#pragma unroll
        for (int i = 0; i < 4; ++i) {
            int q = tid + i * 256;   // 0..1023
            int row = q >> 4;
            int k8 = (q & 15) * 8;
            int rg = rowBase + row;
            if (rg >= NN) rg = NN - 1;
            bf16x8 raw = *(const bf16x8*)&Inh[(size_t)rg * HD + k8];
            unsigned short o[8];
#pragma unroll
            for (int e = 0; e < 8; ++e) {
                float v = bfu((unsigned short)raw[e]);
                v = fmaxf(v * ssS[k8 + e] + ssS[128 + k8 + e], 0.f);
                o[e] = f2bf(v);
            }
            *(bf16x8*)&Abf[row * SP + k8] = *(bf16x8*)o;
        }
    } else {
#pragma unroll
        for (int i = 0; i < 8; ++i) {
            int q = tid + i * 256;   // float4 units
            int row = q >> 5;
            int c4 = (q & 31) * 4;
            int rg = rowBase + row;
            if (rg >= NN) rg = NN - 1;
            float4 v = *(const float4*)&Inf[(size_t)rg * HD + c4];
            unsigned short* p = &Abf[row * SP + c4];
            p[0] = f2bf(v.x); p[1] = f2bf(v.y); p[2] = f2bf(v.z); p[3] = f2bf(v.w);
        }
    }
#pragma unroll
    for (int i = 0; i < 8; ++i) {
        int q = tid + i * 256;   // short8 units
        int n = q >> 4;
        int k8 = (q & 15) * 8;
        bf16x8 w = *(const bf16x8*)&Wt[n * HD + k8];
        *(bf16x8*)&WtL[n * SP + k8] = w;
    }
    __syncthreads();
    int lane = tid & 63;
    int wv = tid >> 6;
    int quad = lane >> 4;
    int lrow = wv * 16 + (lane & 15);
    f32x4 acc[8];
#pragma unroll
    for (int c = 0; c < 8; ++c) acc[c] = (f32x4){0.f, 0.f, 0.f, 0.f};
#pragma unroll
    for (int qk = 0; qk < 4; ++qk) {
        int ko = quad * 8 + qk * 32;
        bf16x8 bfr = *(const bf16x8*)&Abf[lrow * SP + ko];
#pragma unroll
        for (int c = 0; c < 8; ++c) {
            bf16x8 afr = *(const bf16x8*)&WtL[(c * 16 + (lane & 15)) * SP + ko];
            acc[c] = __builtin_amdgcn_mfma_f32_16x16x32_bf16(afr, bfr, acc[c], 0, 0, 0);
        }
    }
    int grow = rowBase + lrow;
    if (grow < NN) {
        float di = dinv[grow];
#pragma unroll
        for (int c = 0; c < 8; ++c) {
            ushort4 o;
            o.x = f2bf(acc[c][0] * di);
            o.y = f2bf(acc[c][1] * di);
            o.z = f2bf(acc[c][2] * di);
            o.w = f2bf(acc[c][3] * di);
            *(ushort4*)&Th[(size_t)grow * HD + c * 16 + quad * 4] = o;
        }
    }
}

// ---------------- Aggregate + fused BN stats ----------------
// A(bf16)[d] = dinv[d]*(sum Ts[s] + Ts[d]) + b. NN % 4 == 0, so every block's
// 4 waves are active (safe barriers). Per-block per-feature sum/sumsq reduced
// in LDS then 256 global atomics into compact stats (removes colstats' 12.8MB
// A re-read per layer).
__global__ __launch_bounds__(256, 8) void k_aggregate(const uint2* __restrict__ T2,
                                                      const int* __restrict__ offsets,
                                                      const int* __restrict__ csr,
                                                      const float* __restrict__ dinv,
                                                      const float* __restrict__ bias,
                                                      unsigned short* __restrict__ Ah,
                                                      float* __restrict__ stats) {
    __shared__ float lsS[128], lsQ[128];
    int d = blockIdx.x * 4 + (threadIdx.x >> 6);
    int l = threadIdx.x & 63;
    int half = l >> 5;
    int li = l & 31;
    if (threadIdx.x < 128) {
        lsS[threadIdx.x] = 0.f;
        lsQ[threadIdx.x] = 0.f;
    }
    __syncthreads();
    int start = offsets[d], end = offsets[d + 1];
    float a0 = 0.f, a1 = 0.f, a2 = 0.f, a3 = 0.f;
    int j = start;
    for (; j + 15 < end; j += 16) {
        int s[8];
        uint2 v[8];
#pragma unroll
        for (int i = 0; i < 8; ++i) s[i] = csr[j + 2 * i + half];
#pragma unroll
        for (int i = 0; i < 8; ++i) v[i] = T2[(size_t)s[i] * 32 + li];
#pragma unroll
        for (int i = 0; i < 8; ++i) {
            a0 += bf_lo(v[i].x); a1 += bf_hi(v[i].x);
            a2 += bf_lo(v[i].y); a3 += bf_hi(v[i].y);
        }
    }
    for (; j + 7 < end; j += 8) {
        int s0 = csr[j + half];
        int s1 = csr[j + 2 + half];
        int s2 = csr[j + 4 + half];
        int s3 = csr[j + 6 + half];
        uint2 v0 = T2[(size_t)s0 * 32 + li];
        uint2 v1 = T2[(size_t)s1 * 32 + li];
        uint2 v2 = T2[(size_t)s2 * 32 + li];
        uint2 v3 = T2[(size_t)s3 * 32 + li];
        a0 += bf_lo(v0.x); a1 += bf_hi(v0.x); a2 += bf_lo(v0.y); a3 += bf_hi(v0.y);
        a0 += bf_lo(v1.x); a1 += bf_hi(v1.x); a2 += bf_lo(v1.y); a3 += bf_hi(v1.y);
        a0 += bf_lo(v2.x); a1 += bf_hi(v2.x); a2 += bf_lo(v2.y); a3 += bf_hi(v2.y);
        a0 += bf_lo(v3.x); a1 += bf_hi(v3.x); a2 += bf_lo(v3.y); a3 += bf_hi(v3.y);
    }
    for (; j + 1 < end; j += 2) {
        int s0 = csr[j + half];
        uint2 v0 = T2[(size_t)s0 * 32 + li];
        a0 += bf_lo(v0.x); a1 += bf_hi(v0.x); a2 += bf_lo(v0.y); a3 += bf_hi(v0.y);
    }
    if (j < end && half == 0) {
        int s0 = csr[j];
        uint2 v0 = T2[(size_t)s0 * 32 + li];
        a0 += bf_lo(v0.x); a1 += bf_hi(v0.x); a2 += bf_lo(v0.y); a3 += bf_hi(v0.y);
    }
    a0 += __shfl_xor(a0, 32);
    a1 += __shfl_xor(a1, 32);
    a2 += __shfl_xor(a2, 32);
    a3 += __shfl_xor(a3, 32);
    if (half == 0) {
        float di = dinv[d];
        uint2 vd = T2[(size_t)d * 32 + li];
        float4 bs = *(const float4*)&bias[4 * li];
        float v0 = di * (a0 + bf_lo(vd.x)) + bs.x;
        float v1 = di * (a1 + bf_hi(vd.x)) + bs.y;
        float v2 = di * (a2 + bf_lo(vd.y)) + bs.z;
        float v3 = di * (a3 + bf_hi(vd.y)) + bs.w;
        ushort4 o;
        o.x = f2bf(v0); o.y = f2bf(v1); o.z = f2bf(v2); o.w = f2bf(v3);
        *(ushort4*)&Ah[(size_t)d * HD + 4 * li] = o;
        atomicAdd(&lsS[4 * li + 0], v0);
        atomicAdd(&lsS[4 * li + 1], v1);
        atomicAdd(&lsS[4 * li + 2], v2);
        atomicAdd(&lsS[4 * li + 3], v3);
        atomicAdd(&lsQ[4 * li + 0], v0 * v0);
        atomicAdd(&lsQ[4 * li + 1], v1 * v1);
        atomicAdd(&lsQ[4 * li + 2], v2 * v2);
        atomicAdd(&lsQ[4 * li + 3], v3 * v3);
    }
    __syncthreads();
    int t = threadIdx.x;
    if (t < 128) atomicAdd(&stats[t], lsS[t]);
    else atomicAdd(&stats[t], lsQ[t - 128]);
}

// ---------------- Segmented pool (+inline BN of layer 2 from stats) ----------------
__global__ __launch_bounds__(256) void k_pool(const unsigned int* __restrict__ Au,
                                              const int* __restrict__ batch,
                                              const float* __restrict__ stats,
                                              const float* __restrict__ gamma,
                                              const float* __restrict__ beta,
                                              float* __restrict__ pooled) {
    __shared__ float ssP[256];
    int t = threadIdx.x;
    ssP[t] = stats[t];
    __syncthreads();
    if (t < 128) {
        float mu = ssP[t] * (1.f / NN);
        float var = ssP[128 + t] * (1.f / NN) - mu * mu;
        float sc = gamma[t] * rsqrtf(var + EPSV);
        float sh = beta[t] - mu * sc;
        ssP[t] = sc;
        ssP[128 + t] = sh;
    }
    __syncthreads();
    int fu = t & 63;        // uint idx: feats 2fu, 2fu+1
    int half = t >> 6;      // 4 row strides
    int r0 = blockIdx.x * 64;
    int rend = min(r0 + 64, NN);
    float s0 = ssP[2 * fu], s1 = ssP[2 * fu + 1];
    float h0 = ssP[128 + 2 * fu], h1 = ssP[128 + 2 * fu + 1];
    float a0 = 0.f, a1 = 0.f;
    int cg = -1;
    for (int r = r0 + half; r < rend; r += 4) {
        int g = batch[r];
        if (g != cg) {
            if (cg >= 0) {
                atomicAdd(&pooled[(size_t)cg * HD + 2 * fu], a0);
                atomicAdd(&pooled[(size_t)cg * HD + 2 * fu + 1], a1);
            }
            cg = g;
            a0 = 0.f; a1 = 0.f;
        }
        unsigned int v = Au[(size_t)r * 64 + fu];
        a0 += fmaxf(bf_lo(v) * s0 + h0, 0.f);
        a1 += fmaxf(bf_hi(v) * s1 + h1, 0.f);
    }
    if (cg >= 0) {
        atomicAdd(&pooled[(size_t)cg * HD + 2 * fu], a0);
        atomicAdd(&pooled[(size_t)cg * HD + 2 * fu + 1], a1);
    }
}

// ---------------- MLP head ----------------
__global__ __launch_bounds__(128) void k_mlp(const float* __restrict__ pooled,
                                             const int* __restrict__ batch,
                                             const float* __restrict__ gfeat,
                                             const float* __restrict__ M1w,
                                             const float* __restrict__ M1b,
                                             const float* __restrict__ M2w,
                                             const float* __restrict__ M2b,
                                             const float* __restrict__ M3w,
                                             const float* __restrict__ M3b,
                                             float* __restrict__ out) {
    __shared__ int sb[2];
    __shared__ float z[HD + GD];
    __shared__ float z1[MD];
    __shared__ float z2[MD / 2];
    int b = blockIdx.x, t = threadIdx.x;
    if (t < 2) {
        int val = b + t;
        int lo = 0, hi = NN;
        while (lo < hi) {
            int mid = (lo + hi) >> 1;
            if (batch[mid] < val) lo = mid + 1; else hi = mid;
        }
        sb[t] = lo;
    }
    __syncthreads();
    float ic = 1.f / fmaxf((float)(sb[1] - sb[0]), 1.f);
    z[t] = pooled[(size_t)b * HD + t] * ic;
    if (t < GD) z[HD + t] = gfeat[b * GD + t];
    __syncthreads();
    float a = M1b[t];
    for (int k = 0; k < HD + GD; ++k) a += z[k] * M1w[k * MD + t];
    z1[t] = fmaxf(a, 0.f);
    __syncthreads();
    if (t < MD / 2) {
        float a2 = M2b[t];
        for (int k = 0; k < MD; ++k) a2 += z1[k] * M2w[k * (MD / 2) + t];
        z2[t] = fmaxf(a2, 0.f);
    }
    __syncthreads();
    if (t < 64) {
        float p = z2[t] * M3w[t];
#pragma unroll
        for (int off = 32; off; off >>= 1) p += __shfl_down(p, off);
        if (t == 0) out[b] = p + M3b[0];
    }
}

static inline size_t alg(size_t x) { return (x + 255) & ~(size_t)255; }

extern "C" void kernel_launch(void* const* d_in, const int* in_sizes, int n_in,
                              void* d_out, int out_size, void* d_ws, size_t ws_size,
                              hipStream_t stream) {
    const float* x = (const float*)d_in[0];
    const int* ei = (const int*)d_in[1];
    const int* batch = (const int*)d_in[2];
    const float* gf = (const float*)d_in[3];
    const float* W[3] = {(const float*)d_in[4], (const float*)d_in[8], (const float*)d_in[12]};
    const float* bb[3] = {(const float*)d_in[5], (const float*)d_in[9], (const float*)d_in[13]};
    const float* gg[3] = {(const float*)d_in[6], (const float*)d_in[10], (const float*)d_in[14]};
    const float* be[3] = {(const float*)d_in[7], (const float*)d_in[11], (const float*)d_in[15]};
    const float* M1w = (const float*)d_in[16];
    const float* M1b = (const float*)d_in[17];
    const float* M2w = (const float*)d_in[18];
    const float* M2b = (const float*)d_in[19];
    const float* M3w = (const float*)d_in[20];
    const float* M3b = (const float*)d_in[21];
    float* out = (float*)d_out;

    char* w = (char*)d_ws;
    int* bucket_cnt = (int*)w;    w += alg((size_t)NBK * 4);
    float* pooled = (float*)w;    w += alg((size_t)BG * HD * 4);
    float* stats = (float*)w;     w += alg((size_t)3 * 256 * 4);
    size_t zspan = (size_t)(w - (char*)d_ws);   // zero bucket_cnt+pooled+stats in one fill
    int* offsets = (int*)w;       w += alg((size_t)(NN + 1) * 4);
    int* csr = (int*)w;           w += alg((size_t)NE * 4);
    float* dinv = (float*)w;      w += alg((size_t)NN * 4);
    unsigned short* Wt = (unsigned short*)w;  w += alg((size_t)3 * 16384 * 2);
    unsigned int* binned = (unsigned int*)w;  w += alg((size_t)NBK * BCAP * 4);
    unsigned short* Ah = (unsigned short*)w;  w += alg((size_t)NN * HD * 2);
    unsigned short* Th = (unsigned short*)w;  w += alg((size_t)NN * HD * 2);

    const int* src = ei;
    const int* dst = ei + NE;

    hipMemsetAsync(bucket_cnt, 0, zspan, stream);
    k_bin<<<(NE + 2047) / 2048, 256, 0, stream>>>(src, dst, bucket_cnt, binned);
    k_csr<<<NBK + 3, 256, 0, stream>>>(binned, bucket_cnt, offsets, dinv, csr,
                                       W[0], W[1], W[2], Wt);

    for (int L = 0; L < 3; ++L) {
        k_gemm<<<(NN + 63) / 64, 256, 0, stream>>>(x, Ah, Wt + (size_t)L * 16384, Th,
                                                   stats + (L ? (L - 1) * 256 : 0),
                                                   gg[L ? L - 1 : 0], be[L ? L - 1 : 0],
                                                   dinv, L > 0);
        k_aggregate<<<NN / 4, 256, 0, stream>>>((const uint2*)Th, offsets, csr,
                                                dinv, bb[L], Ah, stats + L * 256);
    }

    k_pool<<<(NN + 63) / 64, 256, 0, stream>>>((const unsigned int*)Ah, batch,
                                               stats + 2 * 256, gg[2], be[2], pooled);
    k_mlp<<<BG, 128, 0, stream>>>(pooled, batch, gf, M1w, M1b, M2w, M2b, M3w, M3b, out);
}

// Round 14
// 372.971 us; speedup vs baseline: 3.0663x; 3.0663x over previous
//
#include <hip/hip_runtime.h>

#define NN 50000
#define NE 800000
#define BG 512
#define HD 128
#define GD 32
#define MD 128
#define EPSV 1e-5f
#define NBK 256   // dst buckets
#define BSTR 196  // dst per bucket (196*256 = 50176 >= NN)
#define BCAP 4096 // edge capacity per bucket (mean 3136, sd ~56)
#define SP 136    // LDS row stride (shorts) for gemm tiles
#define CSB 128   // colstats blocks

typedef __attribute__((ext_vector_type(8))) short bf16x8;
typedef __attribute__((ext_vector_type(4))) float f32x4;

// bf16 helpers (RNE pack, cheap unpack)
static __device__ __forceinline__ unsigned short f2bf(float f) {
    unsigned int u = __float_as_uint(f);
    u += 0x7fffu + ((u >> 16) & 1u);
    return (unsigned short)(u >> 16);
}
static __device__ __forceinline__ float bfu(unsigned short v) {
    return __uint_as_float((unsigned int)v << 16);
}
static __device__ __forceinline__ float bf_lo(unsigned int v) {
    return __uint_as_float(v << 16);
}
static __device__ __forceinline__ float bf_hi(unsigned int v) {
    return __uint_as_float(v & 0xffff0000u);
}

// ---------------- Pass 1: bin edges by dst bucket ----------------
__global__ __launch_bounds__(256) void k_bin(const int* __restrict__ src,
                                             const int* __restrict__ dst,
                                             int* __restrict__ bucket_cnt,
                                             unsigned int* __restrict__ binned) {
    __shared__ int hcnt[NBK];
    __shared__ int hbase[NBK];
    int tid = threadIdx.x;
    int e0 = blockIdx.x * 2048;
    unsigned int pv[8];
    int bk[8], rk[8];
#pragma unroll
    for (int i = 0; i < 8; ++i) {
        int e = e0 + i * 256 + tid;
        if (e < NE) {
            int s = src[e];
            int d = dst[e];
            bk[i] = d / BSTR;
            pv[i] = ((unsigned int)(d - bk[i] * BSTR) << 16) | (unsigned int)s;
        } else {
            bk[i] = -1;
        }
    }
    hcnt[tid] = 0;
    __syncthreads();
#pragma unroll
    for (int i = 0; i < 8; ++i)
        if (bk[i] >= 0) rk[i] = atomicAdd(&hcnt[bk[i]], 1);
    __syncthreads();
    hbase[tid] = atomicAdd(&bucket_cnt[tid], hcnt[tid]);
    __syncthreads();
#pragma unroll
    for (int i = 0; i < 8; ++i)
        if (bk[i] >= 0)
            binned[(size_t)bk[i] * BCAP + hbase[bk[i]] + rk[i]] = pv[i];
}

// ---------------- CSR build (blocks 0..255) + W transpose (blocks 256..258) ----------------
__global__ __launch_bounds__(256) void k_csr(const unsigned int* __restrict__ binned,
                                             const int* __restrict__ bucket_cnt,
                                             int* __restrict__ offsets,
                                             float* __restrict__ dinv,
                                             int* __restrict__ csr,
                                             const float* __restrict__ W0,
                                             const float* __restrict__ W1,
                                             const float* __restrict__ W2,
                                             unsigned short* __restrict__ Wt) {
    __shared__ unsigned short sW[128 * 130];
    __shared__ int ls[256];
    __shared__ int h[BSTR];
    __shared__ int cur[BSTR];
    __shared__ int bpre_s;
    int b = blockIdx.x, t = threadIdx.x;
    if (b >= NBK) {
        const float* Wsrc = (b == NBK) ? W0 : ((b == NBK + 1) ? W1 : W2);
#pragma unroll
        for (int i = 0; i < 64; ++i) {
            int idx = i * 256 + t;
            int k = idx >> 7, n = idx & 127;
            sW[n * 130 + k] = f2bf(Wsrc[idx]);
        }
        __syncthreads();
        unsigned short* o = Wt + (size_t)(b - NBK) * 16384;
#pragma unroll
        for (int i = 0; i < 64; ++i) {
            int idx = i * 256 + t;
            int n = idx >> 7, k = idx & 127;
            o[idx] = sW[n * 130 + k];
        }
        return;
    }
    int bc = bucket_cnt[t];
    ls[t] = bc;
    __syncthreads();
    for (int off = 1; off < 256; off <<= 1) {
        int c0 = ls[t];
        int add = (t >= off) ? ls[t - off] : 0;
        __syncthreads();
        ls[t] = c0 + add;
        __syncthreads();
    }
    if (t == b) bpre_s = ls[t] - bc;
    if (t < BSTR) h[t] = 0;
    __syncthreads();
    int bpre = bpre_s;
    int nb = bucket_cnt[b];
    const unsigned int* base = binned + (size_t)b * BCAP;
    for (int e = t; e < nb; e += 256)
        atomicAdd(&h[base[e] >> 16], 1);
    __syncthreads();
    int c = (t < BSTR) ? h[t] : 0;
    ls[t] = c;
    __syncthreads();
    for (int off = 1; off < 256; off <<= 1) {
        int c0 = ls[t];
        int add = (t >= off) ? ls[t - off] : 0;
        __syncthreads();
        ls[t] = c0 + add;
        __syncthreads();
    }
    int node = b * BSTR + t;
    if (t < BSTR) {
        int excl = ls[t] - c + bpre;
        cur[t] = excl;
        if (node < NN) {
            offsets[node] = excl;
            dinv[node] = rsqrtf((float)(c + 1));  // in-degree + self loop
            if (node == NN - 1) offsets[NN] = NE;
        }
    }
    __syncthreads();
    for (int e = t; e < nb; e += 256) {
        unsigned int v = base[e];
        int pos = atomicAdd(&cur[v >> 16], 1);
        csr[pos] = (int)(v & 0xffffu);
    }
}

// ---------------- MFMA GEMM (LDS-staged): Th(bf16) = dinv[row] * (BNReLU?(In) @ W) ----------------
// LDS staging: Wt fragments shared across the block's 4 waves (removing it
// regressed R11 — reuse is across waves). BN scales from compact stats[256].
__global__ __launch_bounds__(256) void k_gemm(const float* __restrict__ Inf,
                                              const unsigned short* __restrict__ Inh,
                                              const unsigned short* __restrict__ Wt,
                                              unsigned short* __restrict__ Th,
                                              const float* __restrict__ stats,
                                              const float* __restrict__ gamma,
                                              const float* __restrict__ beta,
                                              const float* __restrict__ dinv,
                                              int useBN) {
    __shared__ unsigned short Abf[64 * SP];
    __shared__ unsigned short WtL[128 * SP];
    __shared__ float ssS[256];
    int tid = threadIdx.x;
    int rowBase = blockIdx.x * 64;
    if (useBN) {
        ssS[tid] = stats[tid];
        __syncthreads();
        if (tid < 128) {
            float mu = ssS[tid] * (1.f / NN);
            float var = ssS[128 + tid] * (1.f / NN) - mu * mu;
            float sc = gamma[tid] * rsqrtf(var + EPSV);
            float sh = beta[tid] - mu * sc;
            ssS[tid] = sc;
            ssS[128 + tid] = sh;
        }
        __syncthreads();
#pragma unroll
        for (int i = 0; i < 4; ++i) {
            int q = tid + i * 256;   // 0..1023
            int row = q >> 4;
            int k8 = (q & 15) * 8;
            int rg = rowBase + row;
            if (rg >= NN) rg = NN - 1;
            bf16x8 raw = *(const bf16x8*)&Inh[(size_t)rg * HD + k8];
            unsigned short o[8];
#pragma unroll
            for (int e = 0; e < 8; ++e) {
                float v = bfu((unsigned short)raw[e]);
                v = fmaxf(v * ssS[k8 + e] + ssS[128 + k8 + e], 0.f);
                o[e] = f2bf(v);
            }
            *(bf16x8*)&Abf[row * SP + k8] = *(bf16x8*)o;
        }
    } else {
#pragma unroll
        for (int i = 0; i < 8; ++i) {
            int q = tid + i * 256;   // float4 units
            int row = q >> 5;
            int c4 = (q & 31) * 4;
            int rg = rowBase + row;
            if (rg >= NN) rg = NN - 1;
            float4 v = *(const float4*)&Inf[(size_t)rg * HD + c4];
            unsigned short* p = &Abf[row * SP + c4];
            p[0] = f2bf(v.x); p[1] = f2bf(v.y); p[2] = f2bf(v.z); p[3] = f2bf(v.w);
        }
    }
#pragma unroll
    for (int i = 0; i < 8; ++i) {
        int q = tid + i * 256;   // short8 units
        int n = q >> 4;
        int k8 = (q & 15) * 8;
        bf16x8 w = *(const bf16x8*)&Wt[n * HD + k8];
        *(bf16x8*)&WtL[n * SP + k8] = w;
    }
    __syncthreads();
    int lane = tid & 63;
    int wv = tid >> 6;
    int quad = lane >> 4;
    int lrow = wv * 16 + (lane & 15);
    f32x4 acc[8];
#pragma unroll
    for (int c = 0; c < 8; ++c) acc[c] = (f32x4){0.f, 0.f, 0.f, 0.f};
#pragma unroll
    for (int qk = 0; qk < 4; ++qk) {
        int ko = quad * 8 + qk * 32;
        bf16x8 bfr = *(const bf16x8*)&Abf[lrow * SP + ko];
#pragma unroll
        for (int c = 0; c < 8; ++c) {
            bf16x8 afr = *(const bf16x8*)&WtL[(c * 16 + (lane & 15)) * SP + ko];
            acc[c] = __builtin_amdgcn_mfma_f32_16x16x32_bf16(afr, bfr, acc[c], 0, 0, 0);
        }
    }
    int grow = rowBase + lrow;
    if (grow < NN) {
        float di = dinv[grow];
#pragma unroll
        for (int c = 0; c < 8; ++c) {
            ushort4 o;
            o.x = f2bf(acc[c][0] * di);
            o.y = f2bf(acc[c][1] * di);
            o.z = f2bf(acc[c][2] * di);
            o.w = f2bf(acc[c][3] * di);
            *(ushort4*)&Th[(size_t)grow * HD + c * 16 + quad * 4] = o;
        }
    }
}

// ---------------- Aggregate: A(bf16)[d] = dinv[d]*(sum Ts[s] + Ts[d]) + b ----------------
__global__ __launch_bounds__(256, 8) void k_aggregate(const uint2* __restrict__ T2,
                                                      const int* __restrict__ offsets,
                                                      const int* __restrict__ csr,
                                                      const float* __restrict__ dinv,
                                                      const float* __restrict__ bias,
                                                      unsigned short* __restrict__ Ah) {
    int d = blockIdx.x * 4 + (threadIdx.x >> 6);
    int l = threadIdx.x & 63;
    int half = l >> 5;
    int li = l & 31;
    if (d >= NN) return;
    int start = offsets[d], end = offsets[d + 1];
    float a0 = 0.f, a1 = 0.f, a2 = 0.f, a3 = 0.f;
    int j = start;
    for (; j + 15 < end; j += 16) {
        int s[8];
        uint2 v[8];
#pragma unroll
        for (int i = 0; i < 8; ++i) s[i] = csr[j + 2 * i + half];
#pragma unroll
        for (int i = 0; i < 8; ++i) v[i] = T2[(size_t)s[i] * 32 + li];
#pragma unroll
        for (int i = 0; i < 8; ++i) {
            a0 += bf_lo(v[i].x); a1 += bf_hi(v[i].x);
            a2 += bf_lo(v[i].y); a3 += bf_hi(v[i].y);
        }
    }
    for (; j + 7 < end; j += 8) {
        int s0 = csr[j + half];
        int s1 = csr[j + 2 + half];
        int s2 = csr[j + 4 + half];
        int s3 = csr[j + 6 + half];
        uint2 v0 = T2[(size_t)s0 * 32 + li];
        uint2 v1 = T2[(size_t)s1 * 32 + li];
        uint2 v2 = T2[(size_t)s2 * 32 + li];
        uint2 v3 = T2[(size_t)s3 * 32 + li];
        a0 += bf_lo(v0.x); a1 += bf_hi(v0.x); a2 += bf_lo(v0.y); a3 += bf_hi(v0.y);
        a0 += bf_lo(v1.x); a1 += bf_hi(v1.x); a2 += bf_lo(v1.y); a3 += bf_hi(v1.y);
        a0 += bf_lo(v2.x); a1 += bf_hi(v2.x); a2 += bf_lo(v2.y); a3 += bf_hi(v2.y);
        a0 += bf_lo(v3.x); a1 += bf_hi(v3.x); a2 += bf_lo(v3.y); a3 += bf_hi(v3.y);
    }
    for (; j + 1 < end; j += 2) {
        int s0 = csr[j + half];
        uint2 v0 = T2[(size_t)s0 * 32 + li];
        a0 += bf_lo(v0.x); a1 += bf_hi(v0.x); a2 += bf_lo(v0.y); a3 += bf_hi(v0.y);
    }
    if (j < end && half == 0) {
        int s0 = csr[j];
        uint2 v0 = T2[(size_t)s0 * 32 + li];
        a0 += bf_lo(v0.x); a1 += bf_hi(v0.x); a2 += bf_lo(v0.y); a3 += bf_hi(v0.y);
    }
    a0 += __shfl_xor(a0, 32);
    a1 += __shfl_xor(a1, 32);
    a2 += __shfl_xor(a2, 32);
    a3 += __shfl_xor(a3, 32);
    if (half == 0) {
        float di = dinv[d];
        uint2 vd = T2[(size_t)d * 32 + li];
        float4 bs = *(const float4*)&bias[4 * li];
        ushort4 o;
        o.x = f2bf(di * (a0 + bf_lo(vd.x)) + bs.x);
        o.y = f2bf(di * (a1 + bf_hi(vd.x)) + bs.y);
        o.z = f2bf(di * (a2 + bf_lo(vd.y)) + bs.z);
        o.w = f2bf(di * (a3 + bf_hi(vd.y)) + bs.w);
        *(ushort4*)&Ah[(size_t)d * HD + 4 * li] = o;
    }
}

// ---------------- BN stats over bf16 A -> compact stats[256] via atomics ----------------
__global__ __launch_bounds__(256) void k_colstats(const uint2* __restrict__ A2,
                                                  float* __restrict__ stats) {
    int li = threadIdx.x & 31;   // feats 4li..4li+3
    int rr = threadIdx.x >> 5;   // 8 row subgroups
    float4 s = {0.f, 0.f, 0.f, 0.f}, q = {0.f, 0.f, 0.f, 0.f};
    for (int row = blockIdx.x * 8 + rr; row < NN; row += CSB * 8) {
        uint2 u = A2[(size_t)row * 32 + li];
        float x0 = bf_lo(u.x), x1 = bf_hi(u.x), x2 = bf_lo(u.y), x3 = bf_hi(u.y);
        s.x += x0; s.y += x1; s.z += x2; s.w += x3;
        q.x += x0 * x0; q.y += x1 * x1; q.z += x2 * x2; q.w += x3 * x3;
    }
    __shared__ float4 lsum[256], lqum[256];
    lsum[threadIdx.x] = s;
    lqum[threadIdx.x] = q;
    __syncthreads();
    if (rr == 0) {
        float4 a = lsum[li];
#pragma unroll
        for (int g = 1; g < 8; ++g) {
            float4 b = lsum[g * 32 + li];
            a.x += b.x; a.y += b.y; a.z += b.z; a.w += b.w;
        }
        atomicAdd(&stats[4 * li + 0], a.x);
        atomicAdd(&stats[4 * li + 1], a.y);
        atomicAdd(&stats[4 * li + 2], a.z);
        atomicAdd(&stats[4 * li + 3], a.w);
    } else if (rr == 1) {
        float4 a = lqum[li];
#pragma unroll
        for (int g = 1; g < 8; ++g) {
            float4 b = lqum[g * 32 + li];
            a.x += b.x; a.y += b.y; a.z += b.z; a.w += b.w;
        }
        atomicAdd(&stats[128 + 4 * li + 0], a.x);
        atomicAdd(&stats[128 + 4 * li + 1], a.y);
        atomicAdd(&stats[128 + 4 * li + 2], a.z);
        atomicAdd(&stats[128 + 4 * li + 3], a.w);
    }
}

// ---------------- Segmented pool (+inline BN of layer 2 from stats) ----------------
__global__ __launch_bounds__(256) void k_pool(const unsigned int* __restrict__ Au,
                                              const int* __restrict__ batch,
                                              const float* __restrict__ stats,
                                              const float* __restrict__ gamma,
                                              const float* __restrict__ beta,
                                              float* __restrict__ pooled) {
    __shared__ float ssP[256];
    int t = threadIdx.x;
    ssP[t] = stats[t];
    __syncthreads();
    if (t < 128) {
        float mu = ssP[t] * (1.f / NN);
        float var = ssP[128 + t] * (1.f / NN) - mu * mu;
        float sc = gamma[t] * rsqrtf(var + EPSV);
        float sh = beta[t] - mu * sc;
        ssP[t] = sc;
        ssP[128 + t] = sh;
    }
    __syncthreads();
    int fu = t & 63;        // uint idx: feats 2fu, 2fu+1
    int half = t >> 6;      // 4 row strides
    int r0 = blockIdx.x * 64;
    int rend = min(r0 + 64, NN);
    float s0 = ssP[2 * fu], s1 = ssP[2 * fu + 1];
    float h0 = ssP[128 + 2 * fu], h1 = ssP[128 + 2 * fu + 1];
    float a0 = 0.f, a1 = 0.f;
    int cg = -1;
    for (int r = r0 + half; r < rend; r += 4) {
        int g = batch[r];
        if (g != cg) {
            if (cg >= 0) {
                atomicAdd(&pooled[(size_t)cg * HD + 2 * fu], a0);
                atomicAdd(&pooled[(size_t)cg * HD + 2 * fu + 1], a1);
            }
            cg = g;
            a0 = 0.f; a1 = 0.f;
        }
        unsigned int v = Au[(size_t)r * 64 + fu];
        a0 += fmaxf(bf_lo(v) * s0 + h0, 0.f);
        a1 += fmaxf(bf_hi(v) * s1 + h1, 0.f);
    }
    if (cg >= 0) {
        atomicAdd(&pooled[(size_t)cg * HD + 2 * fu], a0);
        atomicAdd(&pooled[(size_t)cg * HD + 2 * fu + 1], a1);
    }
}

// ---------------- MLP head ----------------
__global__ __launch_bounds__(128) void k_mlp(const float* __restrict__ pooled,
                                             const int* __restrict__ batch,
                                             const float* __restrict__ gfeat,
                                             const float* __restrict__ M1w,
                                             const float* __restrict__ M1b,
                                             const float* __restrict__ M2w,
                                             const float* __restrict__ M2b,
                                             const float* __restrict__ M3w,
                                             const float* __restrict__ M3b,
                                             float* __restrict__ out) {
    __shared__ int sb[2];
    __shared__ float z[HD + GD];
    __shared__ float z1[MD];
    __shared__ float z2[MD / 2];
    int b = blockIdx.x, t = threadIdx.x;
    if (t < 2) {
        int val = b + t;
        int lo = 0, hi = NN;
        while (lo < hi) {
            int mid = (lo + hi) >> 1;
            if (batch[mid] < val) lo = mid + 1; else hi = mid;
        }
        sb[t] = lo;
    }
    __syncthreads();
    float ic = 1.f / fmaxf((float)(sb[1] - sb[0]), 1.f);
    z[t] = pooled[(size_t)b * HD + t] * ic;
    if (t < GD) z[HD + t] = gfeat[b * GD + t];
    __syncthreads();
    float a = M1b[t];
    for (int k = 0; k < HD + GD; ++k) a += z[k] * M1w[k * MD + t];
    z1[t] = fmaxf(a, 0.f);
    __syncthreads();
    if (t < MD / 2) {
        float a2 = M2b[t];
        for (int k = 0; k < MD; ++k) a2 += z1[k] * M2w[k * (MD / 2) + t];
        z2[t] = fmaxf(a2, 0.f);
    }
    __syncthreads();
    if (t < 64) {
        float p = z2[t] * M3w[t];
#pragma unroll
        for (int off = 32; off; off >>= 1) p += __shfl_down(p, off);
        if (t == 0) out[b] = p + M3b[0];
    }
}

static inline size_t alg(size_t x) { return (x + 255) & ~(size_t)255; }

extern "C" void kernel_launch(void* const* d_in, const int* in_sizes, int n_in,
                              void* d_out, int out_size, void* d_ws, size_t ws_size,
                              hipStream_t stream) {
    const float* x = (const float*)d_in[0];
    const int* ei = (const int*)d_in[1];
    const int* batch = (const int*)d_in[2];
    const float* gf = (const float*)d_in[3];
    const float* W[3] = {(const float*)d_in[4], (const float*)d_in[8], (const float*)d_in[12]};
    const float* bb[3] = {(const float*)d_in[5], (const float*)d_in[9], (const float*)d_in[13]};
    const float* gg[3] = {(const float*)d_in[6], (const float*)d_in[10], (const float*)d_in[14]};
    const float* be[3] = {(const float*)d_in[7], (const float*)d_in[11], (const float*)d_in[15]};
    const float* M1w = (const float*)d_in[16];
    const float* M1b = (const float*)d_in[17];
    const float* M2w = (const float*)d_in[18];
    const float* M2b = (const float*)d_in[19];
    const float* M3w = (const float*)d_in[20];
    const float* M3b = (const float*)d_in[21];
    float* out = (float*)d_out;

    char* w = (char*)d_ws;
    int* bucket_cnt = (int*)w;    w += alg((size_t)NBK * 4);
    float* pooled = (float*)w;    w += alg((size_t)BG * HD * 4);
    float* stats = (float*)w;     w += alg((size_t)3 * 256 * 4);
    size_t zspan = (size_t)(w - (char*)d_ws);   // zero bucket_cnt+pooled+stats in one fill
    int* offsets = (int*)w;       w += alg((size_t)(NN + 1) * 4);
    int* csr = (int*)w;           w += alg((size_t)NE * 4);
    float* dinv = (float*)w;      w += alg((size_t)NN * 4);
    unsigned short* Wt = (unsigned short*)w;  w += alg((size_t)3 * 16384 * 2);
    unsigned int* binned = (unsigned int*)w;  w += alg((size_t)NBK * BCAP * 4);
    unsigned short* Ah = (unsigned short*)w;  w += alg((size_t)NN * HD * 2);
    unsigned short* Th = (unsigned short*)w;  w += alg((size_t)NN * HD * 2);

    const int* src = ei;
    const int* dst = ei + NE;

    hipMemsetAsync(bucket_cnt, 0, zspan, stream);
    k_bin<<<(NE + 2047) / 2048, 256, 0, stream>>>(src, dst, bucket_cnt, binned);
    k_csr<<<NBK + 3, 256, 0, stream>>>(binned, bucket_cnt, offsets, dinv, csr,
                                       W[0], W[1], W[2], Wt);

    for (int L = 0; L < 3; ++L) {
        k_gemm<<<(NN + 63) / 64, 256, 0, stream>>>(x, Ah, Wt + (size_t)L * 16384, Th,
                                                   stats + (L ? (L - 1) * 256 : 0),
                                                   gg[L ? L - 1 : 0], be[L ? L - 1 : 0],
                                                   dinv, L > 0);
        k_aggregate<<<(NN + 3) / 4, 256, 0, stream>>>((const uint2*)Th, offsets, csr,
                                                      dinv, bb[L], Ah);
        k_colstats<<<CSB, 256, 0, stream>>>((const uint2*)Ah, stats + L * 256);
    }

    k_pool<<<(NN + 63) / 64, 256, 0, stream>>>((const unsigned int*)Ah, batch,
                                               stats + 2 * 256, gg[2], be[2], pooled);
    k_mlp<<<BG, 128, 0, stream>>>(pooled, batch, gf, M1w, M1b, M2w, M2b, M3w, M3b, out);
}